// Round 4
// baseline (364.415 us; speedup 1.0000x reference)
//
#include <hip/hip_runtime.h>

// out[b,j,h] = (1/N) * sum_i sum_g W[b,i,j,h,g] * x[b,i,g]
// B=16, N=32, H=64.  W (256 MiB f32) is streamed exactly once -> HBM-bound.
// Roofline: 268 MB / 6.3 TB/s ~= 43 us.
// One block per (b,j): 512 blocks x 512 threads = 2 blocks/CU, 16 waves/CU.
// Each i-step reads the contiguous 16 KB tile W[b,i,j,:,:] with wave-wide
// float4 loads (perfectly coalesced); x[b,:,:] staged once in LDS (8 KB).

#define B_ 16
#define N_ 32
#define H_ 64

__global__ __launch_bounds__(512) void msg_kernel(const float* __restrict__ W,
                                                  const float* __restrict__ X,
                                                  float* __restrict__ out) {
    const int j = blockIdx.x;   // 0..31
    const int b = blockIdx.y;   // 0..15
    const int t = threadIdx.x;  // 0..511

    // Stage x[b,:,:] (32*64 floats = 8 KB = 512 float4) into LDS.
    __shared__ float xs[N_ * H_];
    {
        const float4* xg = (const float4*)(X + b * (N_ * H_));
        ((float4*)xs)[t] = xg[t];
    }
    __syncthreads();

    // W[b,i,j,:,:] is 64x64 floats = 1024 float4; thread t owns flat float4
    // indices {t, t+512}.  Flat float offset 4f = m*2048 + 4t:
    //   h = m*32 + (t>>4),  g = 4*(t&15)..+3
    float acc0 = 0.f, acc1 = 0.f;
    const int gq   = (t & 15);   // float4 index within the g-row
    const int hsub = (t >> 4);   // 0..31

    const float4* Wb = (const float4*)W + ((b * N_ + 0) * N_ + j) * (H_ * H_ / 4);
    const int istride = N_ * (H_ * H_ / 4);  // float4 per i step (512 KB)
    const float4* xs4 = (const float4*)xs;

    #pragma unroll 4
    for (int i = 0; i < N_; ++i) {
        const float4* Wt = Wb + i * istride;
        const float4 x4 = xs4[i * 16 + gq];   // 16-lane broadcast, conflict-free
        const float4 w0 = Wt[t];
        const float4 w1 = Wt[t + 512];
        acc0 += w0.x * x4.x + w0.y * x4.y + w0.z * x4.z + w0.w * x4.w;
        acc1 += w1.x * x4.x + w1.y * x4.y + w1.z * x4.z + w1.w * x4.w;
    }

    // Sum over the 16 lanes sharing (t>>4); xor offsets 1,2,4,8 stay inside
    // each wave-aligned 16-lane group.
    #pragma unroll
    for (int off = 1; off <= 8; off <<= 1) {
        acc0 += __shfl_xor(acc0, off, 64);
        acc1 += __shfl_xor(acc1, off, 64);
    }

    if ((t & 15) == 0) {
        float* o = out + (b * N_ + j) * H_;
        const float s = 1.0f / (float)N_;
        o[hsub]      = acc0 * s;   // h = 0..31
        o[32 + hsub] = acc1 * s;   // h = 32..63
    }
}

extern "C" void kernel_launch(void* const* d_in, const int* in_sizes, int n_in,
                              void* d_out, int out_size, void* d_ws, size_t ws_size,
                              hipStream_t stream) {
    const float* W = (const float*)d_in[0];  // [B,N,N,H,H] f32
    const float* X = (const float*)d_in[1];  // [B,N,H]     f32
    float* out = (float*)d_out;              // [B,N,H]     f32

    dim3 grid(N_, B_);   // (j, b) = 512 blocks
    dim3 block(512);
    msg_kernel<<<grid, block, 0, stream>>>(W, X, out);
}

// Round 7
// 332.726 us; speedup vs baseline: 1.0952x; 1.0952x over previous
//
#include <hip/hip_runtime.h>

// out[b,j,h] = (1/N) * sum_i sum_g W[b,i,j,h,g] * x[b,i,g]
// B=16, N=32, H=64.  W (256 MiB f32) streamed exactly once -> HBM-bound.
// Roofline: 268 MB / 6.3 TB/s ~= 43 us.
// One block per (b,j): 512 blocks x 512 threads, 16 waves/CU.
// W loads are NONTEMPORAL (nt): zero reuse, so don't allocate in L2/L3 --
// avoids forced writebacks of the dirty 1-GiB ws-poison lines the harness
// leaves in L3 before every timed replay.

#define B_ 16
#define N_ 32
#define H_ 64

typedef float f4v __attribute__((ext_vector_type(4)));

__global__ __launch_bounds__(512) void msg_kernel(const float* __restrict__ W,
                                                  const float* __restrict__ X,
                                                  float* __restrict__ out) {
    const int j = blockIdx.x;   // 0..31
    const int b = blockIdx.y;   // 0..15
    const int t = threadIdx.x;  // 0..511

    // Stage x[b,:,:] (32*64 floats = 8 KB = 512 f4v) into LDS (normal loads:
    // X is reused across the 32 j-blocks of this b).
    __shared__ f4v xs4[N_ * H_ / 4];
    xs4[t] = ((const f4v*)(X + b * (N_ * H_)))[t];
    __syncthreads();

    // W[b,i,j,:,:] is 64x64 floats = 1024 f4v; thread t owns flat f4v
    // indices {t, t+512}.  Flat float offset 4f = m*2048 + 4t:
    //   h = m*32 + (t>>4),  g = 4*(t&15)..+3
    float acc0 = 0.f, acc1 = 0.f;
    const int gq   = (t & 15);   // f4v index within the g-row
    const int hsub = (t >> 4);   // 0..31

    const f4v* Wb = (const f4v*)W + ((b * N_ + 0) * N_ + j) * (H_ * H_ / 4);
    const int istride = N_ * (H_ * H_ / 4);  // f4v per i step (512 KB)

    #pragma unroll 4
    for (int i = 0; i < N_; ++i) {
        const f4v* Wt = Wb + i * istride;
        const f4v x4 = xs4[i * 16 + gq];   // 16-lane broadcast, conflict-free
        const f4v w0 = __builtin_nontemporal_load(Wt + t);
        const f4v w1 = __builtin_nontemporal_load(Wt + t + 512);
        acc0 += w0.x * x4.x + w0.y * x4.y + w0.z * x4.z + w0.w * x4.w;
        acc1 += w1.x * x4.x + w1.y * x4.y + w1.z * x4.z + w1.w * x4.w;
    }

    // Sum over the 16 lanes sharing (t>>4); xor offsets 1,2,4,8 stay inside
    // each wave-aligned 16-lane group.
    #pragma unroll
    for (int off = 1; off <= 8; off <<= 1) {
        acc0 += __shfl_xor(acc0, off, 64);
        acc1 += __shfl_xor(acc1, off, 64);
    }

    if ((t & 15) == 0) {
        float* o = out + (b * N_ + j) * H_;
        const float s = 1.0f / (float)N_;
        o[hsub]      = acc0 * s;   // h = 0..31
        o[32 + hsub] = acc1 * s;   // h = 32..63
    }
}

extern "C" void kernel_launch(void* const* d_in, const int* in_sizes, int n_in,
                              void* d_out, int out_size, void* d_ws, size_t ws_size,
                              hipStream_t stream) {
    const float* W = (const float*)d_in[0];  // [B,N,N,H,H] f32
    const float* X = (const float*)d_in[1];  // [B,N,H]     f32
    float* out = (float*)d_out;              // [B,N,H]     f32

    dim3 grid(N_, B_);   // (j, b) = 512 blocks
    dim3 block(512);
    msg_kernel<<<grid, block, 0, stream>>>(W, X, out);
}